// Round 1
// baseline (2436.803 us; speedup 1.0000x reference)
//
#include <hip/hip_runtime.h>
#include <hip/hip_bf16.h>

typedef __attribute__((ext_vector_type(4))) float  f32x4;
typedef __attribute__((ext_vector_type(8))) short  s16x8;
typedef __attribute__((ext_vector_type(4))) short  s16x4;

#define NV 8192
#define NE 8192
#define DIM 512

__device__ inline short f2bf(float x) {
    unsigned u = __float_as_uint(x);
    u += 0x7fffu + ((u >> 16) & 1u);   // round-to-nearest-even
    return (short)(u >> 16);
}

// ---------------- gate[e] = sum_c H_e[e,c] * p[c] ----------------
__global__ void gate_kernel(const float* __restrict__ He, const float* __restrict__ p,
                            float* __restrict__ gate) {
    int row  = blockIdx.x * 4 + (threadIdx.x >> 6);
    int lane = threadIdx.x & 63;
    const float* r = He + (size_t)row * DIM + lane * 8;
    float4 a0 = *(const float4*)r;
    float4 a1 = *(const float4*)(r + 4);
    float4 p0 = *(const float4*)(p + lane * 8);
    float4 p1 = *(const float4*)(p + lane * 8 + 4);
    float s = a0.x*p0.x + a0.y*p0.y + a0.z*p0.z + a0.w*p0.w
            + a1.x*p1.x + a1.y*p1.y + a1.z*p1.z + a1.w*p1.w;
    #pragma unroll
    for (int off = 32; off; off >>= 1) s += __shfl_down(s, off);
    if (lane == 0) gate[row] = s;
}

// ------------- Tg = bf16(T * gate[col]), Tb = bf16(T) -------------
__global__ void convert_T(const float* __restrict__ T, const float* __restrict__ gate,
                          short* __restrict__ Tg, short* __restrict__ Tb) {
    size_t gid  = (size_t)blockIdx.x * blockDim.x + threadIdx.x;
    size_t base = gid * 8;
    int col = (int)(base & (NE - 1));
    float4 t0 = *(const float4*)(T + base);
    float4 t1 = *(const float4*)(T + base + 4);
    float4 g0 = *(const float4*)(gate + col);
    float4 g1 = *(const float4*)(gate + col + 4);
    s16x8 vb, vg;
    vb[0]=f2bf(t0.x); vb[1]=f2bf(t0.y); vb[2]=f2bf(t0.z); vb[3]=f2bf(t0.w);
    vb[4]=f2bf(t1.x); vb[5]=f2bf(t1.y); vb[6]=f2bf(t1.z); vb[7]=f2bf(t1.w);
    vg[0]=f2bf(t0.x*g0.x); vg[1]=f2bf(t0.y*g0.y); vg[2]=f2bf(t0.z*g0.z); vg[3]=f2bf(t0.w*g0.w);
    vg[4]=f2bf(t1.x*g1.x); vg[5]=f2bf(t1.y*g1.y); vg[6]=f2bf(t1.z*g1.z); vg[7]=f2bf(t1.w*g1.w);
    *(s16x8*)(Tb + base) = vb;
    *(s16x8*)(Tg + base) = vg;
}

// ------------- HWb[k][j] = bf16( sum_c H_v[k,c] * W[c,j] ) -------------
__global__ void hv_weight(const float* __restrict__ Hv, const float* __restrict__ Wf,
                          short* __restrict__ HWb) {
    int row = blockIdx.x;
    int tid = threadIdx.x;           // 128 threads
    __shared__ float hv[DIM];
    *(float4*)&hv[tid * 4] = *(const float4*)&Hv[(size_t)row * DIM + tid * 4];
    __syncthreads();
    float a0 = 0.f, a1 = 0.f, a2 = 0.f, a3 = 0.f;
    int j = tid * 4;
    const float* w = Wf + j;
    for (int c = 0; c < DIM; ++c) {
        float h = hv[c];
        float4 wv = *(const float4*)(w + (size_t)c * DIM);
        a0 += h * wv.x; a1 += h * wv.y; a2 += h * wv.z; a3 += h * wv.w;
    }
    s16x4 o; o[0]=f2bf(a0); o[1]=f2bf(a1); o[2]=f2bf(a2); o[3]=f2bf(a3);
    *(s16x4*)&HWb[(size_t)row * DIM + j] = o;
}

// ------------- Wt[j][k] = HWb[k][j]  (bf16 transpose) -------------
__global__ void transpose_bf16(const short* __restrict__ HWb, short* __restrict__ Wt) {
    __shared__ short t[64][65];
    int kb = blockIdx.x;   // 0..127
    int jb = blockIdx.y;   // 0..7
    int tid = threadIdx.x; // 256
    int c = tid & 63, r0 = tid >> 6;
    #pragma unroll
    for (int i = 0; i < 16; ++i) {
        int r = i * 4 + r0;
        t[r][c] = HWb[(size_t)(kb * 64 + r) * DIM + jb * 64 + c];
    }
    __syncthreads();
    #pragma unroll
    for (int i = 0; i < 16; ++i) {
        int r = i * 4 + r0;
        Wt[(size_t)(jb * 64 + r) * NE + kb * 64 + c] = t[c][r];
    }
}

// ------------- B^T GEMM: out[i][j] = sum_k A[i][k]*B[j][k], bf16 in, 128x128 tile -------------
// EPI=0: Cb[i][j] = bf16( i==j ? adj[i][j] : adj[i][j]*(0.5*acc+0.5) )
// EPI=1: Cf[i][j] = acc + bias[j]
template<int EPI>
__global__ __launch_bounds__(256)
void gemm_bt(const short* __restrict__ A, const short* __restrict__ B,
             int M, int N, int K,
             const float* __restrict__ adj, short* __restrict__ Cb,
             const float* __restrict__ bias, float* __restrict__ Cf) {
    __shared__ short As[128 * 32];
    __shared__ short Bs[128 * 32];

    // XCD-aware bijective swizzle (grid % 8 == 0 for all our launches)
    int nwg = gridDim.x;
    int bid = blockIdx.x;
    int cpx = nwg >> 3;
    bid = (bid & 7) * cpx + (bid >> 3);

    const int nbn = N >> 7;
    const int bm = (bid / nbn) << 7;
    const int bn = (bid % nbn) << 7;
    const int tid  = threadIdx.x;
    const int lane = tid & 63;
    const int wave = tid >> 6;
    const int wrow = (wave >> 1) * 64;
    const int wcol = (wave & 1) * 64;

    f32x4 acc[4][4] = {};

    const int lrow = lane >> 2;          // row within 16-row chunk
    const int lcol = (lane & 3) * 8;     // k-offset (8 bf16 = 16B)

    for (int k0 = 0; k0 < K; k0 += 32) {
        #pragma unroll
        for (int it = 0; it < 2; ++it) {
            int chunk = it * 4 + wave;
            int row = chunk * 16 + lrow;
            __builtin_amdgcn_global_load_lds(
                (const __attribute__((address_space(1))) void*)(A + (size_t)(bm + row) * K + k0 + lcol),
                (__attribute__((address_space(3))) void*)(As + chunk * 512), 16, 0, 0);
            __builtin_amdgcn_global_load_lds(
                (const __attribute__((address_space(1))) void*)(B + (size_t)(bn + row) * K + k0 + lcol),
                (__attribute__((address_space(3))) void*)(Bs + chunk * 512), 16, 0, 0);
        }
        __syncthreads();

        const int fr = lane & 15, kq = (lane >> 4) * 8;
        s16x8 af[4], bfr[4];
        #pragma unroll
        for (int i = 0; i < 4; ++i) {
            af[i]  = *(const s16x8*)&As[(wrow + i * 16 + fr) * 32 + kq];
            bfr[i] = *(const s16x8*)&Bs[(wcol + i * 16 + fr) * 32 + kq];
        }
        #pragma unroll
        for (int i = 0; i < 4; ++i)
            #pragma unroll
            for (int j = 0; j < 4; ++j)
                acc[i][j] = __builtin_amdgcn_mfma_f32_16x16x32_bf16(af[i], bfr[j], acc[i][j], 0, 0, 0);
        __syncthreads();
    }

    const int fr = lane & 15, fq = (lane >> 4) * 4;
    #pragma unroll
    for (int i = 0; i < 4; ++i) {
        #pragma unroll
        for (int j = 0; j < 4; ++j) {
            int col = bn + wcol + j * 16 + fr;
            #pragma unroll
            for (int v = 0; v < 4; ++v) {
                int row = bm + wrow + i * 16 + fq + v;
                float d = acc[i][j][v];
                if (EPI == 0) {
                    float av = adj[(size_t)row * N + col];
                    float cv = (row == col) ? av : av * (0.5f * d + 0.5f);
                    Cb[(size_t)row * N + col] = f2bf(cv);
                } else {
                    Cf[(size_t)row * N + col] = d + bias[col];
                }
            }
        }
    }
}

extern "C" void kernel_launch(void* const* d_in, const int* in_sizes, int n_in,
                              void* d_out, int out_size, void* d_ws, size_t ws_size,
                              hipStream_t stream) {
    const float* Hv   = (const float*)d_in[0];
    const float* He   = (const float*)d_in[1];
    // d_in[2] = adj_e (unused by the reference)
    const float* adjv = (const float*)d_in[3];
    const float* T    = (const float*)d_in[4];
    const float* Wf   = (const float*)d_in[5];
    const float* p    = (const float*)d_in[6];
    const float* bias = (const float*)d_in[7];
    float* out = (float*)d_out;

    char* ws = (char*)d_ws;
    float* gate = (float*)(ws);                              //   32 KB
    short* HWb  = (short*)(ws + 32768);                      //    8 MB
    short* Wt   = (short*)(ws + 32768 + 8388608);            //    8 MB
    short* Tg   = (short*)(ws + 16809984);                   //  128 MB
    short* Tb   = (short*)(ws + 151027712);                  //  128 MB
    short* Cb   = (short*)(ws + 285245440);                  //  128 MB  (total ~400 MB)

    // second tuple output: H_e passthrough
    hipMemcpyAsync(out + (size_t)NV * DIM, He, (size_t)NE * DIM * sizeof(float),
                   hipMemcpyDeviceToDevice, stream);

    gate_kernel<<<NE / 4, 256, 0, stream>>>(He, p, gate);
    convert_T<<<(NV * (NE / 8)) / 256, 256, 0, stream>>>(T, gate, Tg, Tb);
    hv_weight<<<NV, 128, 0, stream>>>(Hv, Wf, HWb);
    transpose_bf16<<<dim3(NE / 64, DIM / 64), 256, 0, stream>>>(HWb, Wt);

    // C = 0.5*adjusted_A + 0.5*adj_v, fused into epilogue of (Tg @ Tb^T)
    gemm_bt<0><<<(NV / 128) * (NV / 128), 256, 0, stream>>>(
        Tg, Tb, NV, NV, NE, adjv, Cb, nullptr, nullptr);

    // out = C @ HW + bias
    gemm_bt<1><<<(NV / 128) * (DIM / 128), 256, 0, stream>>>(
        Cb, Wt, NV, DIM, NV, nullptr, nullptr, bias, out);
}

// Round 2
// 1192.646 us; speedup vs baseline: 2.0432x; 2.0432x over previous
//
#include <hip/hip_runtime.h>
#include <hip/hip_bf16.h>

typedef __attribute__((ext_vector_type(4))) float  f32x4;
typedef __attribute__((ext_vector_type(8))) short  s16x8;
typedef __attribute__((ext_vector_type(4))) short  s16x4;

#define NV 8192
#define NE 8192
#define DIM 512

__device__ inline short f2bf(float x) {
    unsigned u = __float_as_uint(x);
    u += 0x7fffu + ((u >> 16) & 1u);   // round-to-nearest-even
    return (short)(u >> 16);
}

// ---------------- gate[e] = sum_c H_e[e,c] * p[c] ----------------
__global__ void gate_kernel(const float* __restrict__ He, const float* __restrict__ p,
                            float* __restrict__ gate) {
    int row  = blockIdx.x * 4 + (threadIdx.x >> 6);
    int lane = threadIdx.x & 63;
    const float* r = He + (size_t)row * DIM + lane * 8;
    float4 a0 = *(const float4*)r;
    float4 a1 = *(const float4*)(r + 4);
    float4 p0 = *(const float4*)(p + lane * 8);
    float4 p1 = *(const float4*)(p + lane * 8 + 4);
    float s = a0.x*p0.x + a0.y*p0.y + a0.z*p0.z + a0.w*p0.w
            + a1.x*p1.x + a1.y*p1.y + a1.z*p1.z + a1.w*p1.w;
    #pragma unroll
    for (int off = 32; off; off >>= 1) s += __shfl_down(s, off);
    if (lane == 0) gate[row] = s;
}

// ------------- Tg = bf16(T * gate[col]), Tb = bf16(T) -------------
__global__ void convert_T(const float* __restrict__ T, const float* __restrict__ gate,
                          short* __restrict__ Tg, short* __restrict__ Tb) {
    size_t gid  = (size_t)blockIdx.x * blockDim.x + threadIdx.x;
    size_t base = gid * 8;
    int col = (int)(base & (NE - 1));
    float4 t0 = *(const float4*)(T + base);
    float4 t1 = *(const float4*)(T + base + 4);
    float4 g0 = *(const float4*)(gate + col);
    float4 g1 = *(const float4*)(gate + col + 4);
    s16x8 vb, vg;
    vb[0]=f2bf(t0.x); vb[1]=f2bf(t0.y); vb[2]=f2bf(t0.z); vb[3]=f2bf(t0.w);
    vb[4]=f2bf(t1.x); vb[5]=f2bf(t1.y); vb[6]=f2bf(t1.z); vb[7]=f2bf(t1.w);
    vg[0]=f2bf(t0.x*g0.x); vg[1]=f2bf(t0.y*g0.y); vg[2]=f2bf(t0.z*g0.z); vg[3]=f2bf(t0.w*g0.w);
    vg[4]=f2bf(t1.x*g1.x); vg[5]=f2bf(t1.y*g1.y); vg[6]=f2bf(t1.z*g1.z); vg[7]=f2bf(t1.w*g1.w);
    *(s16x8*)(Tb + base) = vb;
    *(s16x8*)(Tg + base) = vg;
}

// ------------- f32 -> bf16 bulk convert -------------
__global__ void to_bf16(const float* __restrict__ in, short* __restrict__ out) {
    size_t base = ((size_t)blockIdx.x * blockDim.x + threadIdx.x) * 8;
    float4 a = *(const float4*)(in + base);
    float4 b = *(const float4*)(in + base + 4);
    s16x8 v;
    v[0]=f2bf(a.x); v[1]=f2bf(a.y); v[2]=f2bf(a.z); v[3]=f2bf(a.w);
    v[4]=f2bf(b.x); v[5]=f2bf(b.y); v[6]=f2bf(b.z); v[7]=f2bf(b.w);
    *(s16x8*)(out + base) = v;
}

// ------------- WT[c][r] = bf16(W[r][c])  (512x512 transpose-convert) -------------
__global__ void wT_bf16(const float* __restrict__ W, short* __restrict__ WT) {
    __shared__ short t[64][65];
    int rb = blockIdx.x, cb = blockIdx.y;
    int c = threadIdx.x & 63, r0 = threadIdx.x >> 6;
    #pragma unroll
    for (int i = 0; i < 16; ++i) {
        int r = i * 4 + r0;
        t[r][c] = f2bf(W[(size_t)(rb * 64 + r) * DIM + cb * 64 + c]);
    }
    __syncthreads();
    #pragma unroll
    for (int i = 0; i < 16; ++i) {
        int r = i * 4 + r0;
        WT[(size_t)(cb * 64 + r) * DIM + rb * 64 + c] = t[c][r];
    }
}

// ------------- B^T GEMM (128x128 tile) for the small GEMMs -------------
// EPI=1: Cf[i][j] = acc + bias[j]           (f32 out)
// EPI=2: Cb[i][j] = bf16(acc)               (bf16 out)
template<int EPI>
__global__ __launch_bounds__(256)
void gemm_bt(const short* __restrict__ A, const short* __restrict__ B,
             int M, int N, int K,
             short* __restrict__ Cb,
             const float* __restrict__ bias, float* __restrict__ Cf) {
    __shared__ short As[128 * 32];
    __shared__ short Bs[128 * 32];

    int nwg = gridDim.x;
    int bid = blockIdx.x;
    int cpx = nwg >> 3;
    bid = (bid & 7) * cpx + (bid >> 3);

    const int nbn = N >> 7;
    const int bm = (bid / nbn) << 7;
    const int bn = (bid % nbn) << 7;
    const int tid  = threadIdx.x;
    const int lane = tid & 63;
    const int wave = tid >> 6;
    const int wrow = (wave >> 1) * 64;
    const int wcol = (wave & 1) * 64;

    f32x4 acc[4][4] = {};

    const int lrow = lane >> 2;
    const int lcol = (lane & 3) * 8;

    for (int k0 = 0; k0 < K; k0 += 32) {
        #pragma unroll
        for (int it = 0; it < 2; ++it) {
            int chunk = it * 4 + wave;
            int row = chunk * 16 + lrow;
            __builtin_amdgcn_global_load_lds(
                (const __attribute__((address_space(1))) void*)(A + (size_t)(bm + row) * K + k0 + lcol),
                (__attribute__((address_space(3))) void*)(As + chunk * 512), 16, 0, 0);
            __builtin_amdgcn_global_load_lds(
                (const __attribute__((address_space(1))) void*)(B + (size_t)(bn + row) * K + k0 + lcol),
                (__attribute__((address_space(3))) void*)(Bs + chunk * 512), 16, 0, 0);
        }
        __syncthreads();

        const int fr = lane & 15, kq = (lane >> 4) * 8;
        s16x8 af[4], bfr[4];
        #pragma unroll
        for (int i = 0; i < 4; ++i) {
            af[i]  = *(const s16x8*)&As[(wrow + i * 16 + fr) * 32 + kq];
            bfr[i] = *(const s16x8*)&Bs[(wcol + i * 16 + fr) * 32 + kq];
        }
        #pragma unroll
        for (int i = 0; i < 4; ++i)
            #pragma unroll
            for (int j = 0; j < 4; ++j)
                acc[i][j] = __builtin_amdgcn_mfma_f32_16x16x32_bf16(af[i], bfr[j], acc[i][j], 0, 0, 0);
        __syncthreads();
    }

    const int fr = lane & 15, fq = (lane >> 4) * 4;
    #pragma unroll
    for (int i = 0; i < 4; ++i) {
        #pragma unroll
        for (int j = 0; j < 4; ++j) {
            int col = bn + wcol + j * 16 + fr;
            #pragma unroll
            for (int v = 0; v < 4; ++v) {
                int row = bm + wrow + i * 16 + fq + v;
                float d = acc[i][j][v];
                if (EPI == 1) Cf[(size_t)row * N + col] = d + bias[col];
                else          Cb[(size_t)row * N + col] = f2bf(d);
            }
        }
    }
}

// ============ 256x256 8-phase deep-pipelined GEMM (M=N=K=8192, B^T form) ============
// out fused epilogue: Cb[i][j] = bf16( i==j ? adj : adj*(0.5*acc+0.5) )
#define FENCE asm volatile("" ::: "memory")
#define BAR   do { FENCE; __builtin_amdgcn_s_barrier(); FENCE; } while (0)
#define MFMA16(I0, J0)                                                                       \
    _Pragma("unroll") for (int x = 0; x < 4; ++x)                                            \
    _Pragma("unroll") for (int y = 0; y < 2; ++y)                                            \
    _Pragma("unroll") for (int s = 0; s < 2; ++s)                                            \
        acc[(I0)+x][(J0)+y] = __builtin_amdgcn_mfma_f32_16x16x32_bf16(                       \
            af[x][s], bf[(J0)+y][s], acc[(I0)+x][(J0)+y], 0, 0, 0);

__global__ __launch_bounds__(512, 2)
void gemm256(const short* __restrict__ A, const short* __restrict__ B,
             const float* __restrict__ adj, short* __restrict__ Cb) {
    __shared__ short lds[65536];   // 128 KiB: A buf0/buf1 @ 0/16384, B buf0/buf1 @ 32768/49152

    int bid = blockIdx.x;                       // 1024 blocks
    bid = (bid & 7) * 128 + (bid >> 3);         // XCD swizzle (bijective, 1024%8==0)
    const int bm = (bid >> 5) << 8;
    const int bn = (bid & 31) << 8;

    const int tid  = threadIdx.x;
    const int wave = tid >> 6;
    const int lane = tid & 63;
    const int wm = wave >> 2;                   // 0..1  (row half)
    const int wn = wave & 3;                    // 0..3  (col quarter)
    const int fr = lane & 15;
    const int kq = lane >> 4;                   // 0..3
    const int lr = lane >> 3;                   // staging row-in-group
    const int lsl = (lane & 7) ^ lr;            // inverse-swizzled source slot

    // LDS half bases (short indices) this wave reads from
    const int A0o = wm * 8192;
    const int A1o = 16384 + wm * 8192;
    const int B0o = 32768 + ((wn >> 1) << 13);
    const int B1o = B0o + 16384;

    // per-lane global staging bases (row = bm/bn + wave*8 + lr, col slot = lsl)
    const short* aSrc = A + (size_t)(bm + wave * 8 + lr) * 8192 + lsl * 8;
    const short* bSrc = B + (size_t)(bn + wave * 8 + lr) * 8192 + lsl * 8;

    auto stageA = [&](int buf, int h, int kt) {
        const short* s0 = aSrc + ((size_t)h << 20) + ((kt << 6) & 8191);
        short* d = &lds[buf * 16384 + h * 8192 + wave * 512];
        __builtin_amdgcn_global_load_lds((const __attribute__((address_space(1))) void*)s0,
            (__attribute__((address_space(3))) void*)d, 16, 0, 0);
        __builtin_amdgcn_global_load_lds((const __attribute__((address_space(1))) void*)(s0 + (size_t)(64 * 8192)),
            (__attribute__((address_space(3))) void*)(d + 4096), 16, 0, 0);
    };
    auto stageB = [&](int buf, int h, int kt) {
        const short* s0 = bSrc + ((size_t)h << 20) + ((kt << 6) & 8191);
        short* d = &lds[32768 + buf * 16384 + h * 8192 + wave * 512];
        __builtin_amdgcn_global_load_lds((const __attribute__((address_space(1))) void*)s0,
            (__attribute__((address_space(3))) void*)d, 16, 0, 0);
        __builtin_amdgcn_global_load_lds((const __attribute__((address_space(1))) void*)(s0 + (size_t)(64 * 8192)),
            (__attribute__((address_space(3))) void*)(d + 4096), 16, 0, 0);
    };

    auto lda = [&](int base, int i, int ks) -> s16x8 {
        int rl = i * 16 + fr;
        int slot = ((ks << 2) + kq) ^ (rl & 7);
        return *(const s16x8*)&lds[base + rl * 64 + slot * 8];
    };
    auto ldb = [&](int base, int j, int ks) -> s16x8 {
        int rl = ((wn & 1) << 6) + j * 16 + fr;
        int slot = ((ks << 2) + kq) ^ (rl & 7);
        return *(const s16x8*)&lds[base + rl * 64 + slot * 8];
    };

    f32x4 acc[8][4] = {};
    s16x8 af[4][2], bf[4][2];

    // prologue: tile0 (all 4 halves) + tile1 B halves
    stageA(0, 0, 0); stageA(0, 1, 0);
    stageB(0, 0, 0); stageB(0, 1, 0);
    stageB(1, 0, 1); stageB(1, 1, 1);
    asm volatile("s_waitcnt vmcnt(4)" ::: "memory");
    __builtin_amdgcn_s_barrier();
    FENCE;

    #pragma unroll 1
    for (int it = 0; it < 64; ++it) {
        const int kt = it * 2;
        // ---- ph1: buf0 q0 (A i0-3, B j0-1) ---- stage t+1.A0 -> buf1
        #pragma unroll
        for (int x = 0; x < 4; ++x) { af[x][0] = lda(A0o, x, 0); af[x][1] = lda(A0o, x, 1); }
        #pragma unroll
        for (int y = 0; y < 2; ++y) { bf[y][0] = ldb(B0o, y, 0); bf[y][1] = ldb(B0o, y, 1); }
        stageA(1, 0, kt + 1);
        BAR;
        __builtin_amdgcn_s_setprio(1);
        MFMA16(0, 0)
        __builtin_amdgcn_s_setprio(0);
        BAR;
        // ---- ph2: buf0 q1 (B j2-3) ---- stage t+1.A1 -> buf1
        #pragma unroll
        for (int y = 0; y < 2; ++y) { bf[2+y][0] = ldb(B0o, 2+y, 0); bf[2+y][1] = ldb(B0o, 2+y, 1); }
        stageA(1, 1, kt + 1);
        BAR;
        __builtin_amdgcn_s_setprio(1);
        MFMA16(0, 2)
        __builtin_amdgcn_s_setprio(0);
        BAR;
        // ---- ph3: buf0 q2 (A i4-7) ---- stage t+2.B0 -> buf0
        #pragma unroll
        for (int x = 0; x < 4; ++x) { af[x][0] = lda(A0o, 4+x, 0); af[x][1] = lda(A0o, 4+x, 1); }
        stageB(0, 0, kt + 2);
        BAR;
        __builtin_amdgcn_s_setprio(1);
        MFMA16(4, 0)
        __builtin_amdgcn_s_setprio(0);
        BAR;
        // ---- ph4: buf0 q3 ---- stage t+2.B1 -> buf0 ; vmcnt(4)
        stageB(0, 1, kt + 2);
        BAR;
        __builtin_amdgcn_s_setprio(1);
        MFMA16(4, 2)
        __builtin_amdgcn_s_setprio(0);
        asm volatile("s_waitcnt vmcnt(4)" ::: "memory");
        BAR;
        // ---- ph5: buf1 q0 ---- stage t+2.A0 -> buf0
        #pragma unroll
        for (int x = 0; x < 4; ++x) { af[x][0] = lda(A1o, x, 0); af[x][1] = lda(A1o, x, 1); }
        #pragma unroll
        for (int y = 0; y < 2; ++y) { bf[y][0] = ldb(B1o, y, 0); bf[y][1] = ldb(B1o, y, 1); }
        stageA(0, 0, kt + 2);
        BAR;
        __builtin_amdgcn_s_setprio(1);
        MFMA16(0, 0)
        __builtin_amdgcn_s_setprio(0);
        BAR;
        // ---- ph6: buf1 q1 ---- stage t+2.A1 -> buf0
        #pragma unroll
        for (int y = 0; y < 2; ++y) { bf[2+y][0] = ldb(B1o, 2+y, 0); bf[2+y][1] = ldb(B1o, 2+y, 1); }
        stageA(0, 1, kt + 2);
        BAR;
        __builtin_amdgcn_s_setprio(1);
        MFMA16(0, 2)
        __builtin_amdgcn_s_setprio(0);
        BAR;
        // ---- ph7: buf1 q2 ---- stage t+3.B0 -> buf1
        #pragma unroll
        for (int x = 0; x < 4; ++x) { af[x][0] = lda(A1o, 4+x, 0); af[x][1] = lda(A1o, 4+x, 1); }
        stageB(1, 0, kt + 3);
        BAR;
        __builtin_amdgcn_s_setprio(1);
        MFMA16(4, 0)
        __builtin_amdgcn_s_setprio(0);
        BAR;
        // ---- ph8: buf1 q3 ---- stage t+3.B1 -> buf1 ; vmcnt(4)
        stageB(1, 1, kt + 3);
        BAR;
        __builtin_amdgcn_s_setprio(1);
        MFMA16(4, 2)
        __builtin_amdgcn_s_setprio(0);
        asm volatile("s_waitcnt vmcnt(4)" ::: "memory");
        BAR;
    }

    // epilogue: fuse adj -> Cb
    const int fq = kq << 2;
    #pragma unroll
    for (int i = 0; i < 8; ++i) {
        int row0 = bm + wm * 128 + i * 16 + fq;
        #pragma unroll
        for (int j = 0; j < 4; ++j) {
            int col = bn + wn * 64 + j * 16 + fr;
            #pragma unroll
            for (int v = 0; v < 4; ++v) {
                int r = row0 + v;
                float d = acc[i][j][v];
                float av = adj[(size_t)r * 8192 + col];
                float cv = (r == col) ? av : av * (0.5f * d + 0.5f);
                Cb[(size_t)r * 8192 + col] = f2bf(cv);
            }
        }
    }
}

extern "C" void kernel_launch(void* const* d_in, const int* in_sizes, int n_in,
                              void* d_out, int out_size, void* d_ws, size_t ws_size,
                              hipStream_t stream) {
    const float* Hv   = (const float*)d_in[0];
    const float* He   = (const float*)d_in[1];
    // d_in[2] = adj_e (unused by the reference)
    const float* adjv = (const float*)d_in[3];
    const float* T    = (const float*)d_in[4];
    const float* Wf   = (const float*)d_in[5];
    const float* p    = (const float*)d_in[6];
    const float* bias = (const float*)d_in[7];
    float* out = (float*)d_out;

    char* ws = (char*)d_ws;
    float* gate = (float*)(ws);                      //   32 KB
    short* Hvb  = (short*)(ws + 32768);              //    8 MB
    short* Wt   = (short*)(ws + 8421376);            //    8 MB  (HW^T, [512][8192])
    short* Tg   = (short*)(ws + 16809984);           //  128 MB
    short* Tb   = (short*)(ws + 151027712);          //  128 MB
    short* Cb   = (short*)(ws + 285245440);          //  128 MB
    short* WTb  = (short*)(ws + 285245440);          // aliased with Cb: consumed before gemm256 writes Cb

    // second tuple output: H_e passthrough
    hipMemcpyAsync(out + (size_t)NV * DIM, He, (size_t)NE * DIM * sizeof(float),
                   hipMemcpyDeviceToDevice, stream);

    gate_kernel<<<NE / 4, 256, 0, stream>>>(He, p, gate);
    convert_T<<<(NV * (NE / 8)) / 256, 256, 0, stream>>>(T, gate, Tg, Tb);
    to_bf16<<<(NV * DIM / 8) / 256, 256, 0, stream>>>(Hv, Hvb);
    wT_bf16<<<dim3(8, 8), 256, 0, stream>>>(Wf, WTb);

    // Wt[j][k] = sum_c WT[j][c] * Hvb[k][c] = (Hv@W)^T   (M=512, N=8192, K=512)
    gemm_bt<2><<<(DIM / 128) * (NV / 128), 256, 0, stream>>>(
        WTb, Hvb, DIM, NV, DIM, Wt, nullptr, nullptr);

    // C = 0.5*adjusted_A + 0.5*adj_v fused into epilogue of (Tg @ Tb^T)
    gemm256<<<(NV / 256) * (NV / 256), 512, 0, stream>>>(Tg, Tb, adjv, Cb);

    // out = C @ HW + bias   (M=8192, N=512, K=8192)
    gemm_bt<1><<<(NV / 128) * (DIM / 128), 256, 0, stream>>>(
        Cb, Wt, NV, DIM, NV, nullptr, bias, out);
}